// Round 6
// baseline (38126.337 us; speedup 1.0000x reference)
//
#include <hip/hip_runtime.h>

// Problem constants
#define NB   128
#define LSEQ 2048
#define HID  512
#define EMB  256
#define KD   768
// Tiling: 256 blocks = 2 n-groups x 128 h-blocks
// 512 threads = 32 np (n-pairs) x 4 hl x 4 kseg
#define NT    64
#define HT    4
#define NGR   2
#define HBL   128
#define NWG   256
#define NTHR  512
#define WSTR  772            // 772%32=4 -> the 2 hl-rows per wave hit disjoint bank quads
#define HN    (HID*NB)       // one H buffer (65536 floats)
#define RING  4

#define AT_RLX __ATOMIC_RELAXED
#define SCOPE  __HIP_MEMORY_SCOPE_AGENT

__device__ __forceinline__ float dot4(const float4& w, const float4& m) {
    return fmaf(w.x, m.x, fmaf(w.y, m.y, fmaf(w.z, m.z, w.w * m.w)));
}
__device__ __forceinline__ float sigf(float x) { return 1.0f / (1.0f + __expf(-x)); }
__device__ __forceinline__ float tanhfast(float x) { return fmaf(-2.0f, 1.0f / (1.0f + __expf(2.0f * x)), 1.0f); }
__device__ __forceinline__ float2 u2f(unsigned long long u) {
    union { unsigned long long u; float2 f; } c; c.u = u; return c.f;
}
__device__ __forceinline__ unsigned long long f2u(float2 f) {
    union { unsigned long long u; float2 f; } c; c.f = f; return c.u;
}

__global__ void __launch_bounds__(NTHR, 2)
lstm_pers(const int* __restrict__ X, const float* __restrict__ E,
          const float* __restrict__ Ww, const float* __restrict__ Wb,
          float* __restrict__ out, float* __restrict__ ws)
{
    const int tid  = threadIdx.x;
    const int bid  = blockIdx.x;
    const int nb   = bid & (NGR - 1);          // n-group 0..1
    const int hb   = bid >> 1;                 // h-block 0..127
    const int np   = tid & 31;                 // n-pair 0..31
    const int hl   = (tid >> 5) & 3;           // h within block
    const int kseg = tid >> 7;                 // 0..3, wave-pair-uniform
    const int lid  = tid & 127;                // (np,hl) lane id
    const int n0   = nb * NT + np * 2;         // global n (2 consecutive)
    const int hg   = hb * HT + hl;             // global h

    __shared__ float  Wl[16 * WSTR];           // 49,408 B
    __shared__ float2 red[4][2][128];          //  8,192 B

    float* Hring = ws;                          // RING * HN floats (1 MB)
    int*   flags = (int*)(ws + RING * HN);      // [nb][HBL] per-block epoch flags

    // ---- stage W slice into LDS (16 rows: g*4+h) ----
    for (int i = tid; i < 16 * (KD / 4); i += NTHR) {
        int r = i / (KD / 4), c4 = i - r * (KD / 4);
        int g = r >> 2, h = r & 3;
        float4 v = *((const float4*)(Ww + (size_t)(g * HID + hb * HT + h) * KD) + c4);
        *(float4*)(Wl + r * WSTR + c4 * 4) = v;
    }
    // ---- zero H(0) slice (ring slot 0): relaxed bypass stores (kseg 0) ----
    if (kseg == 0)
        __hip_atomic_store((unsigned long long*)&Hring[hg * NB + n0], 0ull, AT_RLX, SCOPE);

    float bF = 0, bI = 0, bO = 0, bT = 0;
    if (kseg == 0) {
        bF = Wb[0 * HID + hg]; bI = Wb[1 * HID + hg];
        bO = Wb[2 * HID + hg]; bT = Wb[3 * HID + hg];
    }
    float c0 = 0, c1 = 0;                       // cell state (kseg-0 threads, 2 n's)

    // syncthreads drains vmcnt(0) (zero-stores ack'd at LLC) before the flag.
    // flags start poisoned 0xAAAAAAAA (negative) -> signed compares work.
    __syncthreads();
    if (tid == 0) __hip_atomic_store(&flags[nb * HBL + hb], 0, AT_RLX, SCOPE);

    const float* Wr0 = Wl + (0 * 4 + hl) * WSTR;
    const float* Wr1 = Wl + (1 * 4 + hl) * WSTR;
    const float* Wr2 = Wl + (2 * 4 + hl) * WSTR;
    const float* Wr3 = Wl + (3 * 4 + hl) * WSTR;
    const int kb = kseg * 128;                  // H-part k base (128 k's per kseg)
    const int jb = kseg * 64;                   // E-part j base (64 j's per kseg)

    for (int t = 0; t < LSEQ; ++t) {
        float2 a0 = {0,0}, a1 = {0,0}, a2 = {0,0}, a3 = {0,0};

        // ---- E-part first (cached reads, no H dependency; hides producer tail) ----
        {
            int x0 = X[(n0 + 0) * LSEQ + t];
            int x1 = X[(n0 + 1) * LSEQ + t];
            const float* e0 = E + (size_t)x0 * EMB;
            const float* e1 = E + (size_t)x1 * EMB;
            #pragma unroll 4
            for (int jj = 0; jj < 64; jj += 4) {
                int j = jb + jj;
                float4 m0 = *(const float4*)(e0 + j);
                float4 m1 = *(const float4*)(e1 + j);
                float4 w0 = *(const float4*)(Wr0 + HID + j);
                float4 w1 = *(const float4*)(Wr1 + HID + j);
                float4 w2 = *(const float4*)(Wr2 + HID + j);
                float4 w3 = *(const float4*)(Wr3 + HID + j);
                a0.x += dot4(w0, m0); a0.y += dot4(w0, m1);
                a1.x += dot4(w1, m0); a1.y += dot4(w1, m1);
                a2.x += dot4(w2, m0); a2.y += dot4(w2, m1);
                a3.x += dot4(w3, m0); a3.y += dot4(w3, m1);
            }
        }

        // ---- poll: threads 0..127 each watch ONE flag of our n-group ----
        if (tid < HBL) {
            const int* fp = flags + nb * HBL + tid;
            while (__hip_atomic_load(fp, AT_RLX, SCOPE) < t)
                __builtin_amdgcn_s_sleep(1);
        }
        __syncthreads();

        const float* Hc = Hring + (t & (RING - 1)) * HN;
        float*       Hw = Hring + ((t + 1) & (RING - 1)) * HN;

        // ---- H-part: 128 k's, relaxed bypass 8B loads (always fresh from LLC) ----
        #pragma unroll 4
        for (int kk = 0; kk < 128; kk += 4) {
            int k = kb + kk;
            unsigned long long r0 = __hip_atomic_load((const unsigned long long*)&Hc[(k + 0) * NB + n0], AT_RLX, SCOPE);
            unsigned long long r1 = __hip_atomic_load((const unsigned long long*)&Hc[(k + 1) * NB + n0], AT_RLX, SCOPE);
            unsigned long long r2 = __hip_atomic_load((const unsigned long long*)&Hc[(k + 2) * NB + n0], AT_RLX, SCOPE);
            unsigned long long r3 = __hip_atomic_load((const unsigned long long*)&Hc[(k + 3) * NB + n0], AT_RLX, SCOPE);
            float2 h0 = u2f(r0), h1 = u2f(r1), h2 = u2f(r2), h3 = u2f(r3);
            float4 w0 = *(const float4*)(Wr0 + k);
            float4 w1 = *(const float4*)(Wr1 + k);
            float4 w2 = *(const float4*)(Wr2 + k);
            float4 w3 = *(const float4*)(Wr3 + k);
            a0.x = fmaf(w0.x, h0.x, fmaf(w0.y, h1.x, fmaf(w0.z, h2.x, fmaf(w0.w, h3.x, a0.x))));
            a0.y = fmaf(w0.x, h0.y, fmaf(w0.y, h1.y, fmaf(w0.z, h2.y, fmaf(w0.w, h3.y, a0.y))));
            a1.x = fmaf(w1.x, h0.x, fmaf(w1.y, h1.x, fmaf(w1.z, h2.x, fmaf(w1.w, h3.x, a1.x))));
            a1.y = fmaf(w1.x, h0.y, fmaf(w1.y, h1.y, fmaf(w1.z, h2.y, fmaf(w1.w, h3.y, a1.y))));
            a2.x = fmaf(w2.x, h0.x, fmaf(w2.y, h1.x, fmaf(w2.z, h2.x, fmaf(w2.w, h3.x, a2.x))));
            a2.y = fmaf(w2.x, h0.y, fmaf(w2.y, h1.y, fmaf(w2.z, h2.y, fmaf(w2.w, h3.y, a2.y))));
            a3.x = fmaf(w3.x, h0.x, fmaf(w3.y, h1.x, fmaf(w3.z, h2.x, fmaf(w3.w, h3.x, a3.x))));
            a3.y = fmaf(w3.x, h0.y, fmaf(w3.y, h1.y, fmaf(w3.z, h2.y, fmaf(w3.w, h3.y, a3.y))));
        }

        // ---- cross-kseg reduction (4 -> 1): 2 syncs, 8KB ----
        if (kseg >= 2) {                         // ksegs 2,3 write slots 0,1
            int s = kseg - 2;
            red[0][s][lid] = a0; red[1][s][lid] = a1;
            red[2][s][lid] = a2; red[3][s][lid] = a3;
        }
        __syncthreads();
        if (kseg < 2) {                          // ksegs 0,1 absorb slot (kseg)
            float2 r;
            r = red[0][kseg][lid]; a0.x += r.x; a0.y += r.y;
            r = red[1][kseg][lid]; a1.x += r.x; a1.y += r.y;
            r = red[2][kseg][lid]; a2.x += r.x; a2.y += r.y;
            r = red[3][kseg][lid]; a3.x += r.x; a3.y += r.y;
        }
        if (kseg == 1) {                         // kseg1 rewrites its own slot (same thread)
            red[0][1][lid] = a0; red[1][1][lid] = a1;
            red[2][1][lid] = a2; red[3][1][lid] = a3;
        }
        __syncthreads();
        if (kseg == 0) {
            float2 r;
            r = red[0][1][lid]; a0.x += r.x; a0.y += r.y;
            r = red[1][1][lid]; a1.x += r.x; a1.y += r.y;
            r = red[2][1][lid]; a2.x += r.x; a2.y += r.y;
            r = red[3][1][lid]; a3.x += r.x; a3.y += r.y;

            // ---- gates + state update + H publish (128 threads, 2 n's each) ----
            float F, I, O, T, h0, h1;
            F = sigf(a0.x + bF); I = sigf(a1.x + bI); O = sigf(a2.x + bO); T = tanhfast(a3.x + bT);
            c0 = fmaf(F, c0, I * T); h0 = O * tanhfast(c0);
            F = sigf(a0.y + bF); I = sigf(a1.y + bI); O = sigf(a2.y + bO); T = tanhfast(a3.y + bT);
            c1 = fmaf(F, c1, I * T); h1 = O * tanhfast(c1);
            __hip_atomic_store((unsigned long long*)&Hw[hg * NB + n0],
                               f2u(make_float2(h0, h1)), AT_RLX, SCOPE);
            if (t == LSEQ - 1) {
                __hip_atomic_store(&out[(size_t)(n0 + 0) * HID + hg], h0, AT_RLX, SCOPE);
                __hip_atomic_store(&out[(size_t)(n0 + 1) * HID + hg], h1, AT_RLX, SCOPE);
            }
        }

        // syncthreads drains every wave's vmcnt(0): h-stores are ack'd at the LLC
        // before tid0's relaxed flag store below -> any consumer that sees the
        // flag reads fresh H via bypass loads. No acquire/release/inv anywhere.
        __syncthreads();
        if (tid == 0)
            __hip_atomic_store(&flags[nb * HBL + hb], t + 1, AT_RLX, SCOPE);
    }
}

extern "C" void kernel_launch(void* const* d_in, const int* in_sizes, int n_in,
                              void* d_out, int out_size, void* d_ws, size_t ws_size,
                              hipStream_t stream) {
    const int*   X   = (const int*)d_in[0];
    const float* E   = (const float*)d_in[1];
    const float* Ww  = (const float*)d_in[2];
    const float* Wb  = (const float*)d_in[3];
    float*       out = (float*)d_out;
    float*       ws  = (float*)d_ws;
    void* args[] = { (void*)&X, (void*)&E, (void*)&Ww, (void*)&Wb, (void*)&out, (void*)&ws };
    hipError_t e = hipLaunchCooperativeKernel((const void*)lstm_pers, dim3(NWG), dim3(NTHR),
                                              args, 0, stream);
    if (e != hipSuccess) {
        // 256 blocks, 57.6KB LDS -> 1 block/CU, all co-resident on idle 256-CU chip.
        hipLaunchKernelGGL(lstm_pers, dim3(NWG), dim3(NTHR), 0, stream,
                           X, E, Ww, Wb, out, ws);
    }
}